// Round 12
// baseline (286.576 us; speedup 1.0000x reference)
//
#include <hip/hip_runtime.h>
#include <math.h>

#define PI_F 3.14159265358979323846f

typedef float v2f __attribute__((ext_vector_type(2)));

// ---------------------------------------------------------------------------
// GF(2) deferred-CNOT bookkeeping + 4-gate fusion + WAVE-CLOSED PASS PAIRING,
// all at compile time.
// CNOTs are index relabelings in M / M^-1; Rot on wire w pairs p <-> p^col[w],
// role = parity(p & row[w]); same-layer biorthogonality parity(col_j & row_i)
// = delta_ij. Layer-0 Rots fold into the init. Coset representative q is in
// the null space of all 4 roles -> raw coefficients (R9). q is baked into a
// constant table (R12).
// Pairing (R12): for consecutive passes (a,b), find 10-dim V >= masks_a u
// masks_b and w1,w2 in null_a ^ null_b outside V. Lane bits -> basis of
// V ^ null_p (6-dim, exact), wave bits -> w1,w2 shared by both passes. Then
// each wave touches the SAME 1024 amps in both passes -> the a->b boundary
// needs only s_waitcnt lgkmcnt(0), not __syncthreads().
// ---------------------------------------------------------------------------
struct Tab {
    unsigned gmask[15][4];          // pairing masks per pass
    int      ggate[15][4];          // gate index (layer*12 + wire)
    unsigned short qtab[15][256];   // baked representative per (pass, thread)
    unsigned zrow[12];              // final measurement parity rows
    unsigned barrier_mask;          // bit ps: full barrier before pass ps
};

constexpr int rankof(const unsigned* vs, int n) {
    unsigned v[16] = {};
    for (int i = 0; i < n; ++i) v[i] = vs[i];
    int rank = 0;
    for (int c = 0; c < 12; ++c) {
        int sel = -1;
        for (int i = rank; i < n; ++i) if ((v[i] >> c) & 1u) { sel = i; break; }
        if (sel < 0) continue;
        unsigned tmp = v[rank]; v[rank] = v[sel]; v[sel] = tmp;
        for (int i = 0; i < n; ++i)
            if (i != rank && ((v[i] >> c) & 1u)) v[i] ^= v[rank];
        ++rank;
    }
    return rank;
}

// nullspace (12-dim) of nr rows; basis -> out; returns dim.
// Pivots taken from HIGH columns, so out[] for free cols 0..3 have low4 = e_c.
constexpr int nullspace12(const unsigned* rows, int nr, unsigned* out) {
    unsigned R[8] = {};
    for (int i = 0; i < nr; ++i) R[i] = rows[i];
    int pivc[8] = {};
    int rank = 0;
    for (int c = 11; c >= 0; --c) {
        int sel = -1;
        for (int i = rank; i < nr; ++i) if ((R[i] >> c) & 1u) { sel = i; break; }
        if (sel < 0) continue;
        unsigned tmp = R[rank]; R[rank] = R[sel]; R[sel] = tmp;
        for (int i = 0; i < nr; ++i)
            if (i != rank && ((R[i] >> c) & 1u)) R[i] ^= R[rank];
        pivc[rank] = c; ++rank;
    }
    int nn = 0;
    for (int c = 0; c < 12; ++c) {
        bool isp = false;
        for (int i = 0; i < rank; ++i) if (pivc[i] == c) isp = true;
        if (isp) continue;
        unsigned v = 1u << c;
        for (int i = 0; i < rank; ++i)
            if ((R[i] >> c) & 1u) v |= 1u << pivc[i];
        out[nn++] = v;
    }
    return nn;
}

constexpr int rank_low4(const unsigned* vs, int n) {
    unsigned v[8] = {};
    for (int i = 0; i < n; ++i) v[i] = vs[i] & 15u;
    return rankof(v, n);
}

// basis of {x in span(B[0..nb_)) : parity(x & roles[j]) == 0, j<4} -> out
constexpr int span_null_intersect(const unsigned* B, int nb_,
                                  const unsigned* roles, unsigned* out) {
    unsigned C[4] = {};
    for (int j = 0; j < 4; ++j) {
        unsigned row = 0;
        for (int i = 0; i < nb_; ++i)
            if (__builtin_popcount(B[i] & roles[j]) & 1) row |= 1u << i;
        C[j] = row;
    }
    unsigned R[4] = { C[0], C[1], C[2], C[3] };
    int pivc[4] = {};
    int rank = 0;
    for (int c = nb_ - 1; c >= 0; --c) {
        int sel = -1;
        for (int i = rank; i < 4; ++i) if ((R[i] >> c) & 1u) { sel = i; break; }
        if (sel < 0) continue;
        unsigned tmp = R[rank]; R[rank] = R[sel]; R[sel] = tmp;
        for (int i = 0; i < 4; ++i)
            if (i != rank && ((R[i] >> c) & 1u)) R[i] ^= R[rank];
        pivc[rank] = c; ++rank;
    }
    int nn = 0;
    for (int c = 0; c < nb_; ++c) {
        bool isp = false;
        for (int i = 0; i < rank; ++i) if (pivc[i] == c) isp = true;
        if (isp) continue;
        unsigned coef = 1u << c;
        for (int i = 0; i < rank; ++i)
            if ((R[i] >> c) & 1u) coef |= 1u << pivc[i];
        unsigned x = 0;
        for (int i = 0; i < nb_; ++i) if ((coef >> i) & 1u) x ^= B[i];
        out[nn++] = x;
    }
    return nn;
}

constexpr Tab make_tab() {
    Tab tb{};
    unsigned col[12] = {}, row[12] = {};
    for (int w = 0; w < 12; ++w) { col[w] = 1u << (11 - w); row[w] = 1u << (11 - w); }
    // layer 0: Rots folded into init; apply its CNOTs (r = 1)
    for (int w = 0; w < 12; ++w) {
        const int c = w, tg = (w + 1) % 12;
        col[c] ^= col[tg];
        row[tg] ^= row[c];
    }
    // ---- collect per-pass masks / roles (sequential grouping) --------------
    unsigned pm[15][4] = {}, pr[15][4] = {};
    {
        int pass = 0;
        for (int l = 1; l < 6; ++l) {
            for (int grp = 0; grp < 3; ++grp) {
                for (int i = 0; i < 4; ++i) {
                    const int w = grp * 4 + i;
                    pm[pass][i] = col[w];
                    pr[pass][i] = row[w];
                    tb.gmask[pass][i] = col[w];
                    tb.ggate[pass][i] = l * 12 + w;
                }
                ++pass;
            }
            const int r = l + 1;
            for (int w = 0; w < 12; ++w) {
                const int c = w, tg = (w + r) % 12;
                col[c] ^= col[tg];
                row[tg] ^= row[c];
            }
        }
        for (int w = 0; w < 12; ++w) tb.zrow[w] = row[w];
    }
    // ---- unpaired fallback fill --------------------------------------------
    // (lambda-free constexpr: inline helper via loop)
    bool paired_ok[15] = {};
    // try pairing passes (2i, 2i+1)
    for (int pi = 0; pi < 7; ++pi) {
        const int a = 2 * pi, b = 2 * pi + 1;
        unsigned rows8[8] = { pr[a][0], pr[a][1], pr[a][2], pr[a][3],
                              pr[b][0], pr[b][1], pr[b][2], pr[b][3] };
        unsigned nullab[8] = {};
        const int nd = nullspace12(rows8, 8, nullab);
        if (nd < 2) continue;
        unsigned V8[8] = { pm[a][0], pm[a][1], pm[a][2], pm[a][3],
                           pm[b][0], pm[b][1], pm[b][2], pm[b][3] };
        const int r8 = rankof(V8, 8);
        bool done = false;
        for (int relax = 0; relax < 2 && !done; ++relax) {
            for (int i = 0; i < nd && !done; ++i) {
                for (int j = i + 1; j < nd && !done; ++j) {
                    const unsigned w1 = nullab[i], w2 = nullab[j];
                    unsigned test[10] = {};
                    for (int k = 0; k < 8; ++k) test[k] = V8[k];
                    test[8] = w1; test[9] = w2;
                    if (rankof(test, 10) != r8 + 2) continue;
                    // V10: independent subset of V8, extended by unit vectors
                    unsigned V10[10] = {};
                    int nv = 0;
                    {
                        unsigned cur[12] = {};
                        int nc = 0;
                        for (int k = 0; k < 8; ++k) {
                            cur[nc] = V8[k];
                            if (rankof(cur, nc + 1) == nc + 1) ++nc;
                        }
                        for (int k = 0; k < nc; ++k) V10[nv++] = cur[k];
                    }
                    for (int c = 0; c < 12 && nv < 10; ++c) {
                        unsigned chk[13] = {};
                        int ncc = 0;
                        for (int k = 0; k < nv; ++k) chk[ncc++] = V10[k];
                        chk[ncc++] = w1; chk[ncc++] = w2; chk[ncc++] = 1u << c;
                        if (rankof(chk, ncc) == ncc) V10[nv++] = 1u << c;
                    }
                    if (nv < 10) continue;
                    unsigned N6a[10] = {}, N6b[10] = {};
                    const int na  = span_null_intersect(V10, 10, pr[a], N6a);
                    const int nbn = span_null_intersect(V10, 10, pr[b], N6b);
                    if (na != 6 || nbn != 6) continue;
                    if (relax == 0 &&
                        (rank_low4(N6a, 6) < 4 || rank_low4(N6b, 6) < 4)) continue;
                    // safety: full-rank coverage check for both passes
                    unsigned full[12] = {};
                    for (int k = 0; k < 6; ++k) full[k] = N6a[k];
                    full[6] = w1; full[7] = w2;
                    for (int k = 0; k < 4; ++k) full[8 + k] = pm[a][k];
                    if (rankof(full, 12) != 12) continue;
                    for (int k = 0; k < 6; ++k) full[k] = N6b[k];
                    for (int k = 0; k < 4; ++k) full[8 + k] = pm[b][k];
                    if (rankof(full, 12) != 12) continue;
                    // fill qtab for both passes
                    for (int t = 0; t < 256; ++t) {
                        unsigned qa = 0, qb = 0;
                        for (int bb = 0; bb < 6; ++bb)
                            if (t & (1 << bb)) { qa ^= N6a[bb]; qb ^= N6b[bb]; }
                        if (t & 64)  { qa ^= w1; qb ^= w1; }
                        if (t & 128) { qa ^= w2; qb ^= w2; }
                        tb.qtab[a][t] = (unsigned short)qa;
                        tb.qtab[b][t] = (unsigned short)qb;
                    }
                    paired_ok[pi] = true;
                    done = true;
                }
            }
        }
    }
    // ---- unpaired passes: plain nullspace basis -----------------------------
    for (int ps = 0; ps < 15; ++ps) {
        const bool in_pair = (ps < 14) && paired_ok[ps >> 1];
        if (in_pair) continue;
        unsigned nb8[8] = {};
        nullspace12(pr[ps], 4, nb8);   // dim 8; low cols give low4 = e_c
        for (int t = 0; t < 256; ++t) {
            unsigned q = 0;
            for (int bb = 0; bb < 8; ++bb)
                if (t & (1 << bb)) q ^= nb8[bb];
            tb.qtab[ps][t] = (unsigned short)q;
        }
    }
    // ---- barrier mask --------------------------------------------------------
    unsigned bm = 0;
    for (int ps = 0; ps < 15; ++ps) {
        const bool second_of_pair = (ps & 1) && (ps < 14) && paired_ok[ps >> 1];
        if (!second_of_pair) bm |= 1u << ps;
    }
    bm |= 1u;   // always barrier before pass 0 (init handoff)
    tb.barrier_mask = bm;
    return tb;
}

constexpr Tab HT = make_tab();
__constant__ Tab GT = HT;
constexpr unsigned BMASK = HT.barrier_mask;

// pass-ordered Rot coefs: [pass*32 + lev*8 + j]; layer-0 at [480 + w*8 + j].
__device__ float g_coef[576];

__device__ __forceinline__ void rot8(const float* __restrict__ wp, float* o) {
    const float phi = wp[0], th = wp[1], om = wp[2];
    const float hs = 0.5f * (phi + om), hd = 0.5f * (phi - om), ht = 0.5f * th;
    const float ctt = cosf(ht), stt = sinf(ht);
    const float cs = cosf(hs), ss = sinf(hs);
    const float cd = cosf(hd), sd = sinf(hd);
    o[0] = cs * ctt;  o[1] = -ss * ctt;   // u00
    o[2] = -cd * stt; o[3] = -sd * stt;   // u01
    o[4] = cd * stt;  o[5] = -sd * stt;   // u10
    o[6] = cs * ctt;  o[7] = ss * ctt;    // u11
}

__global__ void rot_coef_kernel(const float* __restrict__ weights) {
    const int i = blockIdx.x * blockDim.x + threadIdx.x;
    if (i < 60) {
        const int ps = i >> 2, lev = i & 3;
        const int g = GT.ggate[ps][lev];
        float o[8];
        rot8(weights + g * 3, o);
        #pragma unroll
        for (int j = 0; j < 8; ++j) g_coef[ps * 32 + lev * 8 + j] = o[j];
    } else if (i >= 64 && i < 76) {
        const int w = i - 64;
        float o[8];
        rot8(weights + w * 3, o);
        #pragma unroll
        for (int j = 0; j < 8; ++j) g_coef[480 + w * 8 + j] = o[j];
    }
}

__device__ __forceinline__ v2f cmulv(v2f A, v2f B) {
    return (v2f){ A.x * B.x - A.y * B.y, A.x * B.y + A.y * B.x };
}

// packed complex butterfly (v_pk_fma_f32 path, R11)
__device__ __forceinline__ void bf(v2f& X, v2f& Y,
                                   float Ar, float Ai, float Br, float Bi,
                                   float Cr, float Ci, float Dr, float Di) {
    const v2f x = X, y = Y;
    const v2f xs = { -x.y, x.x };
    const v2f ys = { -y.y, y.x };
    v2f nx = x * (v2f){ Ar, Ar };
    nx = __builtin_elementwise_fma((v2f){ Ai, Ai }, xs, nx);
    nx = __builtin_elementwise_fma((v2f){ Br, Br }, y,  nx);
    nx = __builtin_elementwise_fma((v2f){ Bi, Bi }, ys, nx);
    v2f ny = x * (v2f){ Cr, Cr };
    ny = __builtin_elementwise_fma((v2f){ Ci, Ci }, xs, ny);
    ny = __builtin_elementwise_fma((v2f){ Dr, Dr }, y,  ny);
    ny = __builtin_elementwise_fma((v2f){ Di, Di }, ys, ny);
    X = nx; Y = ny;
}

// ---------------------------------------------------------------------------
// One block (256 threads) per batch element. LDS = exactly the 32 KB state.
// 15 fused passes; paired passes are wave-closed -> only lgkmcnt(0) between.
// ---------------------------------------------------------------------------
__global__ __launch_bounds__(256) void qvl_fused(
    const float* __restrict__ v,        // (B, 512)
    const float* __restrict__ Wc,       // (12, 512)
    const float* __restrict__ bc,       // (12,)
    float* __restrict__ out)            // (B, 12)
{
    __shared__ v2f st[4096];     // 32768 B total LDS
    float* redf = reinterpret_cast<float*>(st);   // overlay (48 floats)

    const int t    = threadIdx.x;
    const int lane = t & 63;
    const int wv   = t >> 6;
    const int b    = blockIdx.x;

    // ---- x_w = tanh(v[b] . Wc[w] + bc[w]) * pi (partials into overlay) -----
    {
        const float2 vv = reinterpret_cast<const float2*>(v + b * 512)[t];
        #pragma unroll
        for (int w = 0; w < 12; ++w) {
            const float2 ww = reinterpret_cast<const float2*>(Wc + w * 512)[t];
            float p = vv.x * ww.x + vv.y * ww.y;
            #pragma unroll
            for (int s = 1; s < 64; s <<= 1) p += __shfl_xor(p, s, 64);
            if (lane == 0) redf[w * 4 + wv] = p;
        }
    }
    __syncthreads();

    // ---- per-wave: lanes 0..11 fold RY(x_w) + layer-0 Rot into (aw, bw) ----
    float awx = 0.0f, awy = 0.0f, bwx = 0.0f, bwy = 0.0f;
    if (lane < 12) {
        const float x = tanhf(redf[lane * 4 + 0] + redf[lane * 4 + 1] +
                              redf[lane * 4 + 2] + redf[lane * 4 + 3] + bc[lane]) * PI_F;
        const float h = 0.5f * x;
        const float c = cosf(h), s = sinf(h);
        const float* c8 = g_coef + 480 + lane * 8;
        awx = c8[0] * c + c8[2] * s;  awy = c8[1] * c + c8[3] * s;
        bwx = c8[4] * c + c8[6] * s;  bwy = c8[5] * c + c8[7] * s;
    }
    __syncthreads();   // overlay reads done before init overwrites st

    // ---- init: product state; p = k*256 + t (t bits -> wires 11..4) --------
    {
        v2f hi = { 1.0f, 0.0f };
        #pragma unroll
        for (int j = 0; j < 8; ++j) {
            const int src = 11 - j;            // wire for p bit j
            const float ax = __shfl(awx, src, 64), ay = __shfl(awy, src, 64);
            const float bx = __shfl(bwx, src, 64), by = __shfl(bwy, src, 64);
            const int bit = (t >> j) & 1;
            hi = cmulv(hi, (v2f){ bit ? bx : ax, bit ? by : ay });
        }
        v2f A3 = { __shfl(awx, 3, 64), __shfl(awy, 3, 64) };
        v2f B3 = { __shfl(bwx, 3, 64), __shfl(bwy, 3, 64) };
        v2f A2 = { __shfl(awx, 2, 64), __shfl(awy, 2, 64) };
        v2f B2 = { __shfl(bwx, 2, 64), __shfl(bwy, 2, 64) };
        v2f A1 = { __shfl(awx, 1, 64), __shfl(awy, 1, 64) };
        v2f B1 = { __shfl(bwx, 1, 64), __shfl(bwy, 1, 64) };
        v2f A0 = { __shfl(awx, 0, 64), __shfl(awy, 0, 64) };
        v2f B0 = { __shfl(bwx, 0, 64), __shfl(bwy, 0, 64) };
        v2f fA[4], fB[4];
        #pragma unroll
        for (int m = 0; m < 4; ++m) {
            fA[m] = cmulv((m & 1) ? B3 : A3, (m & 2) ? B2 : A2);   // p bits 8,9
            fB[m] = cmulv((m & 1) ? B1 : A1, (m & 2) ? B0 : A0);   // p bits 10,11
        }
        #pragma unroll
        for (int k = 0; k < 16; ++k)
            st[k * 256 + t] = cmulv(hi, cmulv(fA[k & 3], fB[k >> 2]));
    }

    // ---- 15 fused passes (layers 1..5, 4 gates each) ------------------------
    unsigned qn = GT.qtab[0][t];
    #pragma unroll 1
    for (int ps = 0; ps < 15; ++ps) {
        unsigned q = qn;
        qn = GT.qtab[(ps + 1 < 15) ? ps + 1 : 0][t];   // prefetch next
        if (BMASK & (1u << ps)) {
            __syncthreads();
        } else {
            // paired boundary: same-wave data only -> drain own DS ops
            asm volatile("s_waitcnt lgkmcnt(0)" ::: "memory");
        }
        const float* cp = g_coef + ps * 32;    // uniform -> s_load
        const unsigned m0 = GT.gmask[ps][0], m1 = GT.gmask[ps][1];
        const unsigned m2 = GT.gmask[ps][2], m3 = GT.gmask[ps][3];

        // Gray-code load chain (one rolling address register)
        unsigned ad = q;
        v2f g0  = st[ad]; ad ^= m0;
        v2f g1  = st[ad]; ad ^= m1;
        v2f g3  = st[ad]; ad ^= m0;
        v2f g2  = st[ad]; ad ^= m2;
        v2f g6  = st[ad]; ad ^= m0;
        v2f g7  = st[ad]; ad ^= m1;
        v2f g5  = st[ad]; ad ^= m0;
        v2f g4  = st[ad]; ad ^= m3;
        v2f g12 = st[ad]; ad ^= m0;
        v2f g13 = st[ad]; ad ^= m1;
        v2f g15 = st[ad]; ad ^= m0;
        v2f g14 = st[ad]; ad ^= m2;
        v2f g10 = st[ad]; ad ^= m0;
        v2f g11 = st[ad]; ad ^= m1;
        v2f g9  = st[ad]; ad ^= m0;
        v2f g8  = st[ad];

        // all representatives have role parity 0 at every level -> raw coefs
        #define BF(X, Y) bf(X, Y, Ar, Ai, Br, Bi, Cr, Ci, Dr, Di)
        { const float Ar = cp[0],  Ai = cp[1],  Br = cp[2],  Bi = cp[3];
          const float Cr = cp[4],  Ci = cp[5],  Dr = cp[6],  Di = cp[7];
          BF(g0,g1); BF(g2,g3); BF(g4,g5); BF(g6,g7);
          BF(g8,g9); BF(g10,g11); BF(g12,g13); BF(g14,g15); }
        { const float Ar = cp[8],  Ai = cp[9],  Br = cp[10], Bi = cp[11];
          const float Cr = cp[12], Ci = cp[13], Dr = cp[14], Di = cp[15];
          BF(g0,g2); BF(g1,g3); BF(g4,g6); BF(g5,g7);
          BF(g8,g10); BF(g9,g11); BF(g12,g14); BF(g13,g15); }
        { const float Ar = cp[16], Ai = cp[17], Br = cp[18], Bi = cp[19];
          const float Cr = cp[20], Ci = cp[21], Dr = cp[22], Di = cp[23];
          BF(g0,g4); BF(g1,g5); BF(g2,g6); BF(g3,g7);
          BF(g8,g12); BF(g9,g13); BF(g10,g14); BF(g11,g15); }
        { const float Ar = cp[24], Ai = cp[25], Br = cp[26], Bi = cp[27];
          const float Cr = cp[28], Ci = cp[29], Dr = cp[30], Di = cp[31];
          BF(g0,g8); BF(g1,g9); BF(g2,g10); BF(g3,g11);
          BF(g4,g12); BF(g5,g13); BF(g6,g14); BF(g7,g15); }
        #undef BF

        // opaque barrier on q: store chain recomputed, not CSE'd with loads
        asm volatile("" : "+v"(q));

        ad = q;
        st[ad] = g0;  ad ^= m0;
        st[ad] = g1;  ad ^= m1;
        st[ad] = g3;  ad ^= m0;
        st[ad] = g2;  ad ^= m2;
        st[ad] = g6;  ad ^= m0;
        st[ad] = g7;  ad ^= m1;
        st[ad] = g5;  ad ^= m0;
        st[ad] = g4;  ad ^= m3;
        st[ad] = g12; ad ^= m0;
        st[ad] = g13; ad ^= m1;
        st[ad] = g15; ad ^= m0;
        st[ad] = g14; ad ^= m2;
        st[ad] = g10; ad ^= m0;
        st[ad] = g11; ad ^= m1;
        st[ad] = g9;  ad ^= m0;
        st[ad] = g8;
    }
    __syncthreads();

    // ---- PauliZ expvals; p = k*256 + t, sign = parity(p & zrow) ------------
    float p2[16];
    #pragma unroll
    for (int k = 0; k < 16; ++k) {
        const v2f aa = st[k * 256 + t];
        p2[k] = aa.x * aa.x + aa.y * aa.y;
    }
    __syncthreads();   // all st reads done before overlay reuse
    #pragma unroll
    for (int w = 0; w < 12; ++w) {
        const unsigned zr = GT.zrow[w];
        const unsigned Aw = (unsigned)__popc((unsigned)t & zr) & 1u;
        const unsigned nm = (zr >> 8) & 0xFu;
        unsigned P = 0u;
        P ^= (nm & 1u) ? 0xAAAAu : 0u;
        P ^= (nm & 2u) ? 0xCCCCu : 0u;
        P ^= (nm & 4u) ? 0xF0F0u : 0u;
        P ^= (nm & 8u) ? 0xFF00u : 0u;
        P ^= Aw ? 0xFFFFu : 0u;
        float z = 0.0f;
        #pragma unroll
        for (int k = 0; k < 16; ++k)
            z += ((P >> k) & 1u) ? -p2[k] : p2[k];
        #pragma unroll
        for (int s = 1; s < 64; s <<= 1) z += __shfl_xor(z, s, 64);
        if (lane == 0) redf[w * 4 + wv] = z;
    }
    __syncthreads();
    if (t < 12)
        out[b * 12 + t] = redf[t * 4 + 0] + redf[t * 4 + 1] +
                          redf[t * 4 + 2] + redf[t * 4 + 3];
}

extern "C" void kernel_launch(void* const* d_in, const int* in_sizes, int n_in,
                              void* d_out, int out_size, void* d_ws, size_t ws_size,
                              hipStream_t stream) {
    (void)n_in; (void)out_size; (void)d_ws; (void)ws_size;
    const float* v   = (const float*)d_in[0];
    const float* Wc  = (const float*)d_in[1];
    const float* bc  = (const float*)d_in[2];
    const float* wts = (const float*)d_in[3];
    float* out = (float*)d_out;

    const int B = in_sizes[0] / 512;
    rot_coef_kernel<<<1, 128, 0, stream>>>(wts);
    qvl_fused<<<B, 256, 0, stream>>>(v, Wc, bc, out);
}

// Round 13
// 257.929 us; speedup vs baseline: 1.1111x; 1.1111x over previous
//
#include <hip/hip_runtime.h>
#include <math.h>

#define PI_F 3.14159265358979323846f

typedef float v2f __attribute__((ext_vector_type(2)));

// ---------------------------------------------------------------------------
// GF(2) deferred-CNOT + 4-gate fusion + wave-closed pass pairing (R12), with
// R13 fix: every representative basis is RREF-aligned over low-4 columns so
// low4(q) == low4(t) exactly -> R11's bank behavior, for paired AND unpaired
// passes. Pairs that cannot be aligned keep a full barrier (no relax path).
// ---------------------------------------------------------------------------
struct Tab {
    unsigned gmask[15][4];          // pairing masks per pass
    int      ggate[15][4];          // gate index (layer*12 + wire)
    unsigned short qtab[15][256];   // baked representative per (pass, thread)
    unsigned zrow[12];              // final measurement parity rows
    unsigned barrier_mask;          // bit ps: full barrier before pass ps
};

constexpr int rankof(const unsigned* vs, int n) {
    unsigned v[16] = {};
    for (int i = 0; i < n; ++i) v[i] = vs[i];
    int rank = 0;
    for (int c = 0; c < 12; ++c) {
        int sel = -1;
        for (int i = rank; i < n; ++i) if ((v[i] >> c) & 1u) { sel = i; break; }
        if (sel < 0) continue;
        unsigned tmp = v[rank]; v[rank] = v[sel]; v[sel] = tmp;
        for (int i = 0; i < n; ++i)
            if (i != rank && ((v[i] >> c) & 1u)) v[i] ^= v[rank];
        ++rank;
    }
    return rank;
}

constexpr int nullspace12(const unsigned* rows, int nr, unsigned* out) {
    unsigned R[8] = {};
    for (int i = 0; i < nr; ++i) R[i] = rows[i];
    int pivc[8] = {};
    int rank = 0;
    for (int c = 11; c >= 0; --c) {
        int sel = -1;
        for (int i = rank; i < nr; ++i) if ((R[i] >> c) & 1u) { sel = i; break; }
        if (sel < 0) continue;
        unsigned tmp = R[rank]; R[rank] = R[sel]; R[sel] = tmp;
        for (int i = 0; i < nr; ++i)
            if (i != rank && ((R[i] >> c) & 1u)) R[i] ^= R[rank];
        pivc[rank] = c; ++rank;
    }
    int nn = 0;
    for (int c = 0; c < 12; ++c) {
        bool isp = false;
        for (int i = 0; i < rank; ++i) if (pivc[i] == c) isp = true;
        if (isp) continue;
        unsigned v = 1u << c;
        for (int i = 0; i < rank; ++i)
            if ((R[i] >> c) & 1u) v |= 1u << pivc[i];
        out[nn++] = v;
    }
    return nn;
}

// basis of {x in span(B[0..nb_)) : parity(x & roles[j]) == 0, j<4} -> out
constexpr int span_null_intersect(const unsigned* B, int nb_,
                                  const unsigned* roles, unsigned* out) {
    unsigned C[4] = {};
    for (int j = 0; j < 4; ++j) {
        unsigned row = 0;
        for (int i = 0; i < nb_; ++i)
            if (__builtin_popcount(B[i] & roles[j]) & 1) row |= 1u << i;
        C[j] = row;
    }
    unsigned R[4] = { C[0], C[1], C[2], C[3] };
    int pivc[4] = {};
    int rank = 0;
    for (int c = nb_ - 1; c >= 0; --c) {
        int sel = -1;
        for (int i = rank; i < 4; ++i) if ((R[i] >> c) & 1u) { sel = i; break; }
        if (sel < 0) continue;
        unsigned tmp = R[rank]; R[rank] = R[sel]; R[sel] = tmp;
        for (int i = 0; i < 4; ++i)
            if (i != rank && ((R[i] >> c) & 1u)) R[i] ^= R[rank];
        pivc[rank] = c; ++rank;
    }
    int nn = 0;
    for (int c = 0; c < nb_; ++c) {
        bool isp = false;
        for (int i = 0; i < rank; ++i) if (pivc[i] == c) isp = true;
        if (isp) continue;
        unsigned coef = 1u << c;
        for (int i = 0; i < rank; ++i)
            if ((R[i] >> c) & 1u) coef |= 1u << pivc[i];
        unsigned x = 0;
        for (int i = 0; i < nb_; ++i) if ((coef >> i) & 1u) x ^= B[i];
        out[nn++] = x;
    }
    return nn;
}

// R13: RREF the n basis vectors over columns 0..3. On success out[c] has
// low4 == e_c (c = 0..3) and out[4..n-1] have low4 == 0 (span unchanged).
constexpr bool align_low4(const unsigned* in, int n, unsigned* out) {
    unsigned v[8] = {};
    for (int i = 0; i < n; ++i) v[i] = in[i];
    int pivr[4] = { -1, -1, -1, -1 };
    for (int c = 0; c < 4; ++c) {
        int sel = -1;
        for (int i = 0; i < n; ++i) {
            bool isp = false;
            for (int j = 0; j < c; ++j) if (pivr[j] == i) isp = true;
            if (!isp && ((v[i] >> c) & 1u)) { sel = i; break; }
        }
        if (sel < 0) return false;
        for (int i = 0; i < n; ++i)
            if (i != sel && ((v[i] >> c) & 1u)) v[i] ^= v[sel];
        pivr[c] = sel;
    }
    int no = 0;
    for (int c = 0; c < 4; ++c) out[no++] = v[pivr[c]];
    for (int i = 0; i < n; ++i) {
        bool isp = false;
        for (int c = 0; c < 4; ++c) if (pivr[c] == i) isp = true;
        if (!isp) out[no++] = v[i];
    }
    return true;
}

constexpr Tab make_tab() {
    Tab tb{};
    unsigned col[12] = {}, row[12] = {};
    for (int w = 0; w < 12; ++w) { col[w] = 1u << (11 - w); row[w] = 1u << (11 - w); }
    for (int w = 0; w < 12; ++w) {           // layer-0 CNOTs (Rots in init)
        const int c = w, tg = (w + 1) % 12;
        col[c] ^= col[tg];
        row[tg] ^= row[c];
    }
    unsigned pm[15][4] = {}, pr[15][4] = {};
    {
        int pass = 0;
        for (int l = 1; l < 6; ++l) {
            for (int grp = 0; grp < 3; ++grp) {
                for (int i = 0; i < 4; ++i) {
                    const int w = grp * 4 + i;
                    pm[pass][i] = col[w];
                    pr[pass][i] = row[w];
                    tb.gmask[pass][i] = col[w];
                    tb.ggate[pass][i] = l * 12 + w;
                }
                ++pass;
            }
            const int r = l + 1;
            for (int w = 0; w < 12; ++w) {
                const int c = w, tg = (w + r) % 12;
                col[c] ^= col[tg];
                row[tg] ^= row[c];
            }
        }
        for (int w = 0; w < 12; ++w) tb.zrow[w] = row[w];
    }
    bool paired_ok[15] = {};
    for (int pi = 0; pi < 7; ++pi) {
        const int a = 2 * pi, b = 2 * pi + 1;
        unsigned rows8[8] = { pr[a][0], pr[a][1], pr[a][2], pr[a][3],
                              pr[b][0], pr[b][1], pr[b][2], pr[b][3] };
        unsigned nullab[8] = {};
        const int nd = nullspace12(rows8, 8, nullab);
        if (nd < 2) continue;
        unsigned V8[8] = { pm[a][0], pm[a][1], pm[a][2], pm[a][3],
                           pm[b][0], pm[b][1], pm[b][2], pm[b][3] };
        const int r8 = rankof(V8, 8);
        bool done = false;
        for (int i = 0; i < nd && !done; ++i) {
            for (int j = i + 1; j < nd && !done; ++j) {
                const unsigned w1 = nullab[i], w2 = nullab[j];
                unsigned test[10] = {};
                for (int k = 0; k < 8; ++k) test[k] = V8[k];
                test[8] = w1; test[9] = w2;
                if (rankof(test, 10) != r8 + 2) continue;
                // V10: independent subset of V8 extended by unit vectors
                unsigned V10[10] = {};
                int nv = 0;
                {
                    unsigned cur[12] = {};
                    int nc = 0;
                    for (int k = 0; k < 8; ++k) {
                        cur[nc] = V8[k];
                        if (rankof(cur, nc + 1) == nc + 1) ++nc;
                    }
                    for (int k = 0; k < nc; ++k) V10[nv++] = cur[k];
                }
                for (int c = 0; c < 12 && nv < 10; ++c) {
                    unsigned chk[13] = {};
                    int ncc = 0;
                    for (int k = 0; k < nv; ++k) chk[ncc++] = V10[k];
                    chk[ncc++] = w1; chk[ncc++] = w2; chk[ncc++] = 1u << c;
                    if (rankof(chk, ncc) == ncc) V10[nv++] = 1u << c;
                }
                if (nv < 10) continue;
                unsigned N6a[10] = {}, N6b[10] = {};
                const int na  = span_null_intersect(V10, 10, pr[a], N6a);
                const int nbn = span_null_intersect(V10, 10, pr[b], N6b);
                if (na != 6 || nbn != 6) continue;
                // R13: STRICT low-4 alignment for both passes, else no pair
                unsigned A6[8] = {}, B6[8] = {};
                if (!align_low4(N6a, 6, A6)) continue;
                if (!align_low4(N6b, 6, B6)) continue;
                // bijectivity safety for both passes
                unsigned full[12] = {};
                for (int k = 0; k < 6; ++k) full[k] = A6[k];
                full[6] = w1; full[7] = w2;
                for (int k = 0; k < 4; ++k) full[8 + k] = pm[a][k];
                if (rankof(full, 12) != 12) continue;
                for (int k = 0; k < 6; ++k) full[k] = B6[k];
                for (int k = 0; k < 4; ++k) full[8 + k] = pm[b][k];
                if (rankof(full, 12) != 12) continue;
                for (int t = 0; t < 256; ++t) {
                    unsigned qa = 0, qb = 0;
                    for (int bb = 0; bb < 6; ++bb)
                        if (t & (1 << bb)) { qa ^= A6[bb]; qb ^= B6[bb]; }
                    if (t & 64)  { qa ^= w1; qb ^= w1; }
                    if (t & 128) { qa ^= w2; qb ^= w2; }
                    tb.qtab[a][t] = (unsigned short)qa;
                    tb.qtab[b][t] = (unsigned short)qb;
                }
                paired_ok[pi] = true;
                done = true;
            }
        }
    }
    // unpaired passes: aligned plain nullspace basis (== R11 bank behavior)
    for (int ps = 0; ps < 15; ++ps) {
        const bool in_pair = (ps < 14) && paired_ok[ps >> 1];
        if (in_pair) continue;
        unsigned nb8[8] = {}, al8[8] = {};
        const int nn = nullspace12(pr[ps], 4, nb8);
        const unsigned* use = nb8;
        if (nn == 8 && align_low4(nb8, 8, al8)) use = al8;
        for (int t = 0; t < 256; ++t) {
            unsigned q = 0;
            for (int bb = 0; bb < 8; ++bb)
                if (t & (1 << bb)) q ^= use[bb];
            tb.qtab[ps][t] = (unsigned short)q;
        }
    }
    unsigned bm = 0;
    for (int ps = 0; ps < 15; ++ps) {
        const bool second_of_pair = (ps & 1) && (ps < 14) && paired_ok[ps >> 1];
        if (!second_of_pair) bm |= 1u << ps;
    }
    bm |= 1u;
    tb.barrier_mask = bm;
    return tb;
}

constexpr Tab HT = make_tab();
__constant__ Tab GT = HT;
constexpr unsigned BMASK = HT.barrier_mask;

// pass-ordered Rot coefs: [pass*32 + lev*8 + j]; layer-0 at [480 + w*8 + j].
__device__ float g_coef[576];

__device__ __forceinline__ void rot8(const float* __restrict__ wp, float* o) {
    const float phi = wp[0], th = wp[1], om = wp[2];
    const float hs = 0.5f * (phi + om), hd = 0.5f * (phi - om), ht = 0.5f * th;
    const float ctt = cosf(ht), stt = sinf(ht);
    const float cs = cosf(hs), ss = sinf(hs);
    const float cd = cosf(hd), sd = sinf(hd);
    o[0] = cs * ctt;  o[1] = -ss * ctt;   // u00
    o[2] = -cd * stt; o[3] = -sd * stt;   // u01
    o[4] = cd * stt;  o[5] = -sd * stt;   // u10
    o[6] = cs * ctt;  o[7] = ss * ctt;    // u11
}

__global__ void rot_coef_kernel(const float* __restrict__ weights) {
    const int i = blockIdx.x * blockDim.x + threadIdx.x;
    if (i < 60) {
        const int ps = i >> 2, lev = i & 3;
        const int g = GT.ggate[ps][lev];
        float o[8];
        rot8(weights + g * 3, o);
        #pragma unroll
        for (int j = 0; j < 8; ++j) g_coef[ps * 32 + lev * 8 + j] = o[j];
    } else if (i >= 64 && i < 76) {
        const int w = i - 64;
        float o[8];
        rot8(weights + w * 3, o);
        #pragma unroll
        for (int j = 0; j < 8; ++j) g_coef[480 + w * 8 + j] = o[j];
    }
}

__device__ __forceinline__ v2f cmulv(v2f A, v2f B) {
    return (v2f){ A.x * B.x - A.y * B.y, A.x * B.y + A.y * B.x };
}

// packed complex butterfly (v_pk_fma_f32 path, R11)
__device__ __forceinline__ void bf(v2f& X, v2f& Y,
                                   float Ar, float Ai, float Br, float Bi,
                                   float Cr, float Ci, float Dr, float Di) {
    const v2f x = X, y = Y;
    const v2f xs = { -x.y, x.x };
    const v2f ys = { -y.y, y.x };
    v2f nx = x * (v2f){ Ar, Ar };
    nx = __builtin_elementwise_fma((v2f){ Ai, Ai }, xs, nx);
    nx = __builtin_elementwise_fma((v2f){ Br, Br }, y,  nx);
    nx = __builtin_elementwise_fma((v2f){ Bi, Bi }, ys, nx);
    v2f ny = x * (v2f){ Cr, Cr };
    ny = __builtin_elementwise_fma((v2f){ Ci, Ci }, xs, ny);
    ny = __builtin_elementwise_fma((v2f){ Dr, Dr }, y,  ny);
    ny = __builtin_elementwise_fma((v2f){ Di, Di }, ys, ny);
    X = nx; Y = ny;
}

// ---------------------------------------------------------------------------
// One block (256 threads) per batch element. LDS = exactly the 32 KB state.
// 15 fused passes; paired passes are wave-closed -> only lgkmcnt(0) between.
// ---------------------------------------------------------------------------
__global__ __launch_bounds__(256) void qvl_fused(
    const float* __restrict__ v,        // (B, 512)
    const float* __restrict__ Wc,       // (12, 512)
    const float* __restrict__ bc,       // (12,)
    float* __restrict__ out)            // (B, 12)
{
    __shared__ v2f st[4096];     // 32768 B total LDS
    float* redf = reinterpret_cast<float*>(st);   // overlay (48 floats)

    const int t    = threadIdx.x;
    const int lane = t & 63;
    const int wv   = t >> 6;
    const int b    = blockIdx.x;

    // ---- x_w = tanh(v[b] . Wc[w] + bc[w]) * pi (partials into overlay) -----
    {
        const float2 vv = reinterpret_cast<const float2*>(v + b * 512)[t];
        #pragma unroll
        for (int w = 0; w < 12; ++w) {
            const float2 ww = reinterpret_cast<const float2*>(Wc + w * 512)[t];
            float p = vv.x * ww.x + vv.y * ww.y;
            #pragma unroll
            for (int s = 1; s < 64; s <<= 1) p += __shfl_xor(p, s, 64);
            if (lane == 0) redf[w * 4 + wv] = p;
        }
    }
    __syncthreads();

    // ---- per-wave: lanes 0..11 fold RY(x_w) + layer-0 Rot into (aw, bw) ----
    float awx = 0.0f, awy = 0.0f, bwx = 0.0f, bwy = 0.0f;
    if (lane < 12) {
        const float x = tanhf(redf[lane * 4 + 0] + redf[lane * 4 + 1] +
                              redf[lane * 4 + 2] + redf[lane * 4 + 3] + bc[lane]) * PI_F;
        const float h = 0.5f * x;
        const float c = cosf(h), s = sinf(h);
        const float* c8 = g_coef + 480 + lane * 8;
        awx = c8[0] * c + c8[2] * s;  awy = c8[1] * c + c8[3] * s;
        bwx = c8[4] * c + c8[6] * s;  bwy = c8[5] * c + c8[7] * s;
    }
    __syncthreads();   // overlay reads done before init overwrites st

    // ---- init: product state; p = k*256 + t (t bits -> wires 11..4) --------
    {
        v2f hi = { 1.0f, 0.0f };
        #pragma unroll
        for (int j = 0; j < 8; ++j) {
            const int src = 11 - j;            // wire for p bit j
            const float ax = __shfl(awx, src, 64), ay = __shfl(awy, src, 64);
            const float bx = __shfl(bwx, src, 64), by = __shfl(bwy, src, 64);
            const int bit = (t >> j) & 1;
            hi = cmulv(hi, (v2f){ bit ? bx : ax, bit ? by : ay });
        }
        v2f A3 = { __shfl(awx, 3, 64), __shfl(awy, 3, 64) };
        v2f B3 = { __shfl(bwx, 3, 64), __shfl(bwy, 3, 64) };
        v2f A2 = { __shfl(awx, 2, 64), __shfl(awy, 2, 64) };
        v2f B2 = { __shfl(bwx, 2, 64), __shfl(bwy, 2, 64) };
        v2f A1 = { __shfl(awx, 1, 64), __shfl(awy, 1, 64) };
        v2f B1 = { __shfl(bwx, 1, 64), __shfl(bwy, 1, 64) };
        v2f A0 = { __shfl(awx, 0, 64), __shfl(awy, 0, 64) };
        v2f B0 = { __shfl(bwx, 0, 64), __shfl(bwy, 0, 64) };
        v2f fA[4], fB[4];
        #pragma unroll
        for (int m = 0; m < 4; ++m) {
            fA[m] = cmulv((m & 1) ? B3 : A3, (m & 2) ? B2 : A2);   // p bits 8,9
            fB[m] = cmulv((m & 1) ? B1 : A1, (m & 2) ? B0 : A0);   // p bits 10,11
        }
        #pragma unroll
        for (int k = 0; k < 16; ++k)
            st[k * 256 + t] = cmulv(hi, cmulv(fA[k & 3], fB[k >> 2]));
    }

    // ---- 15 fused passes (layers 1..5, 4 gates each) ------------------------
    unsigned qn = GT.qtab[0][t];
    #pragma unroll 1
    for (int ps = 0; ps < 15; ++ps) {
        unsigned q = qn;
        qn = GT.qtab[(ps + 1 < 15) ? ps + 1 : 0][t];   // prefetch next
        if (BMASK & (1u << ps)) {
            __syncthreads();
        } else {
            // paired boundary: same-wave data only -> drain own DS ops
            asm volatile("s_waitcnt lgkmcnt(0)" ::: "memory");
        }
        const float* cp = g_coef + ps * 32;    // uniform -> s_load
        const unsigned m0 = GT.gmask[ps][0], m1 = GT.gmask[ps][1];
        const unsigned m2 = GT.gmask[ps][2], m3 = GT.gmask[ps][3];

        // Gray-code load chain (one rolling address register)
        unsigned ad = q;
        v2f g0  = st[ad]; ad ^= m0;
        v2f g1  = st[ad]; ad ^= m1;
        v2f g3  = st[ad]; ad ^= m0;
        v2f g2  = st[ad]; ad ^= m2;
        v2f g6  = st[ad]; ad ^= m0;
        v2f g7  = st[ad]; ad ^= m1;
        v2f g5  = st[ad]; ad ^= m0;
        v2f g4  = st[ad]; ad ^= m3;
        v2f g12 = st[ad]; ad ^= m0;
        v2f g13 = st[ad]; ad ^= m1;
        v2f g15 = st[ad]; ad ^= m0;
        v2f g14 = st[ad]; ad ^= m2;
        v2f g10 = st[ad]; ad ^= m0;
        v2f g11 = st[ad]; ad ^= m1;
        v2f g9  = st[ad]; ad ^= m0;
        v2f g8  = st[ad];

        // all representatives have role parity 0 at every level -> raw coefs
        #define BF(X, Y) bf(X, Y, Ar, Ai, Br, Bi, Cr, Ci, Dr, Di)
        { const float Ar = cp[0],  Ai = cp[1],  Br = cp[2],  Bi = cp[3];
          const float Cr = cp[4],  Ci = cp[5],  Dr = cp[6],  Di = cp[7];
          BF(g0,g1); BF(g2,g3); BF(g4,g5); BF(g6,g7);
          BF(g8,g9); BF(g10,g11); BF(g12,g13); BF(g14,g15); }
        { const float Ar = cp[8],  Ai = cp[9],  Br = cp[10], Bi = cp[11];
          const float Cr = cp[12], Ci = cp[13], Dr = cp[14], Di = cp[15];
          BF(g0,g2); BF(g1,g3); BF(g4,g6); BF(g5,g7);
          BF(g8,g10); BF(g9,g11); BF(g12,g14); BF(g13,g15); }
        { const float Ar = cp[16], Ai = cp[17], Br = cp[18], Bi = cp[19];
          const float Cr = cp[20], Ci = cp[21], Dr = cp[22], Di = cp[23];
          BF(g0,g4); BF(g1,g5); BF(g2,g6); BF(g3,g7);
          BF(g8,g12); BF(g9,g13); BF(g10,g14); BF(g11,g15); }
        { const float Ar = cp[24], Ai = cp[25], Br = cp[26], Bi = cp[27];
          const float Cr = cp[28], Ci = cp[29], Dr = cp[30], Di = cp[31];
          BF(g0,g8); BF(g1,g9); BF(g2,g10); BF(g3,g11);
          BF(g4,g12); BF(g5,g13); BF(g6,g14); BF(g7,g15); }
        #undef BF

        // opaque barrier on q: store chain recomputed, not CSE'd with loads
        asm volatile("" : "+v"(q));

        ad = q;
        st[ad] = g0;  ad ^= m0;
        st[ad] = g1;  ad ^= m1;
        st[ad] = g3;  ad ^= m0;
        st[ad] = g2;  ad ^= m2;
        st[ad] = g6;  ad ^= m0;
        st[ad] = g7;  ad ^= m1;
        st[ad] = g5;  ad ^= m0;
        st[ad] = g4;  ad ^= m3;
        st[ad] = g12; ad ^= m0;
        st[ad] = g13; ad ^= m1;
        st[ad] = g15; ad ^= m0;
        st[ad] = g14; ad ^= m2;
        st[ad] = g10; ad ^= m0;
        st[ad] = g11; ad ^= m1;
        st[ad] = g9;  ad ^= m0;
        st[ad] = g8;
    }
    __syncthreads();

    // ---- PauliZ expvals; p = k*256 + t, sign = parity(p & zrow) ------------
    float p2[16];
    #pragma unroll
    for (int k = 0; k < 16; ++k) {
        const v2f aa = st[k * 256 + t];
        p2[k] = aa.x * aa.x + aa.y * aa.y;
    }
    __syncthreads();   // all st reads done before overlay reuse
    #pragma unroll
    for (int w = 0; w < 12; ++w) {
        const unsigned zr = GT.zrow[w];
        const unsigned Aw = (unsigned)__popc((unsigned)t & zr) & 1u;
        const unsigned nm = (zr >> 8) & 0xFu;
        unsigned P = 0u;
        P ^= (nm & 1u) ? 0xAAAAu : 0u;
        P ^= (nm & 2u) ? 0xCCCCu : 0u;
        P ^= (nm & 4u) ? 0xF0F0u : 0u;
        P ^= (nm & 8u) ? 0xFF00u : 0u;
        P ^= Aw ? 0xFFFFu : 0u;
        float z = 0.0f;
        #pragma unroll
        for (int k = 0; k < 16; ++k)
            z += ((P >> k) & 1u) ? -p2[k] : p2[k];
        #pragma unroll
        for (int s = 1; s < 64; s <<= 1) z += __shfl_xor(z, s, 64);
        if (lane == 0) redf[w * 4 + wv] = z;
    }
    __syncthreads();
    if (t < 12)
        out[b * 12 + t] = redf[t * 4 + 0] + redf[t * 4 + 1] +
                          redf[t * 4 + 2] + redf[t * 4 + 3];
}

extern "C" void kernel_launch(void* const* d_in, const int* in_sizes, int n_in,
                              void* d_out, int out_size, void* d_ws, size_t ws_size,
                              hipStream_t stream) {
    (void)n_in; (void)out_size; (void)d_ws; (void)ws_size;
    const float* v   = (const float*)d_in[0];
    const float* Wc  = (const float*)d_in[1];
    const float* bc  = (const float*)d_in[2];
    const float* wts = (const float*)d_in[3];
    float* out = (float*)d_out;

    const int B = in_sizes[0] / 512;
    rot_coef_kernel<<<1, 128, 0, stream>>>(wts);
    qvl_fused<<<B, 256, 0, stream>>>(v, Wc, bc, out);
}